// Round 5
// baseline (2232.853 us; speedup 1.0000x reference)
//
#include <hip/hip_runtime.h>
#include <math.h>

#define NN 50000
#define NE 600000
#define NG 512

// ================= CSR build (once per launch; edge_index constant across layers) ========
__global__ __launch_bounds__(256)
void deg_count_k(const int* __restrict__ ei, int* __restrict__ deg) {
  int e = blockIdx.x * 256 + threadIdx.x;
  if (e >= NE) return;
  atomicAdd(&deg[ei[NE + e]], 1);
}

__global__ __launch_bounds__(1024)
void scan_k(const int* __restrict__ deg, int* __restrict__ row_ptr, int* __restrict__ cursor) {
  __shared__ int sums[1024];
  const int CH = 49;                 // 1024*49 = 50176 >= 50000
  int t = threadIdx.x;
  int base = t * CH;
  int s = 0;
  for (int i = 0; i < CH; i++) { int idx = base + i; if (idx < NN) s += deg[idx]; }
  sums[t] = s;
  __syncthreads();
  for (int off = 1; off < 1024; off <<= 1) {
    int v = (t >= off) ? sums[t - off] : 0;
    __syncthreads();
    sums[t] += v;
    __syncthreads();
  }
  int prefix = (t == 0) ? 0 : sums[t - 1];
  for (int i = 0; i < CH; i++) {
    int idx = base + i;
    if (idx < NN) { row_ptr[idx] = prefix; cursor[idx] = prefix; prefix += deg[idx]; }
  }
  if (t == 1023) row_ptr[NN] = sums[1023];
}

__global__ __launch_bounds__(256)
void fill_k(const int* __restrict__ ei, int* __restrict__ cursor, int* __restrict__ perm) {
  int e = blockIdx.x * 256 + threadIdx.x;
  if (e >= NE) return;
  int pos = atomicAdd(&cursor[ei[NE + e]], 1);
  perm[pos] = ei[e];
}

// ============== fused gather-mean + SAGE layer, Cout=128 ==================================
// block 256 = 4 waves; wave owns 4 rows; lane owns output cols (2*lane, 2*lane+1).
// Phase A: wave gathers mean of in-neighbors into its private LDS slab (no barrier needed).
// Phase B: 4 x 32KB W chunks (Wl k-lo/hi, Wr k-lo/hi); agg read from LDS, x broadcast from L2.
template<bool WRITE_PRE>
__global__ __launch_bounds__(256)
void fsage128_k(const float* __restrict__ x, const int* __restrict__ row_ptr,
                const int* __restrict__ perm,
                const float* __restrict__ Wl, const float* __restrict__ bl,
                const float* __restrict__ Wr,
                float* __restrict__ out_relu, float* __restrict__ out_pre) {
  __shared__ __align__(16) float sW[64 * 128];    // 32 KB chunk
  __shared__ __align__(16) float sAgg[16][128];   // 8 KB: [wave*4+i][ch]
  int wave = threadIdx.x >> 6;
  int lane = threadIdx.x & 63;
  int r0 = blockIdx.x * 16 + wave * 4;            // 3125 * 16 = 50000
  int co = lane * 2;

  // ---- Phase A: gather mean into sAgg (wave-private slab) ----
#pragma unroll
  for (int i = 0; i < 4; i++) {
    int n = r0 + i;
    int beg = row_ptr[n], end = row_ptr[n + 1];
    float ax0 = 0.f, ay0 = 0.f, ax1 = 0.f, ay1 = 0.f;
    float ax2 = 0.f, ay2 = 0.f, ax3 = 0.f, ay3 = 0.f;
    int e = beg;
    for (; e + 4 <= end; e += 4) {
      int s0 = perm[e + 0], s1 = perm[e + 1], s2 = perm[e + 2], s3 = perm[e + 3];
      float2 v0 = *(const float2*)(x + (size_t)s0 * 128 + co);
      float2 v1 = *(const float2*)(x + (size_t)s1 * 128 + co);
      float2 v2 = *(const float2*)(x + (size_t)s2 * 128 + co);
      float2 v3 = *(const float2*)(x + (size_t)s3 * 128 + co);
      ax0 += v0.x; ay0 += v0.y; ax1 += v1.x; ay1 += v1.y;
      ax2 += v2.x; ay2 += v2.y; ax3 += v3.x; ay3 += v3.y;
    }
    for (; e < end; e++) {
      int s0 = perm[e];
      float2 v = *(const float2*)(x + (size_t)s0 * 128 + co);
      ax0 += v.x; ay0 += v.y;
    }
    float inv = 1.0f / fmaxf((float)(end - beg), 1.0f);
    float2 o = { (ax0 + ax1 + ax2 + ax3) * inv, (ay0 + ay1 + ay2 + ay3) * inv };
    *(float2*)(&sAgg[wave * 4 + i][co]) = o;
  }

  // ---- Phase B: GEMM over 4 chunks ----
  float acc0[4] = {0.f, 0.f, 0.f, 0.f};
  float acc1[4] = {0.f, 0.f, 0.f, 0.f};

  for (int half = 0; half < 4; half++) {
    const float* Wg = (half < 2) ? Wl : Wr;
    int kbase = (half & 1) * 64;
    __syncthreads();
    {
      const float4* g = (const float4*)(Wg + kbase * 128);
      float4* s = (float4*)sW;
      for (int t = threadIdx.x; t < 2048; t += 256) s[t] = g[t];
    }
    __syncthreads();
    bool useLds = (half < 2);
    for (int kb = 0; kb < 8; kb++) {
      int k0 = kb * 8;           // within chunk
      int kk = kbase + k0;       // global k
      float w0[8], w1[8];
#pragma unroll
      for (int j = 0; j < 8; j++) {
        float2 wp = *(const float2*)(&sW[(k0 + j) * 128 + co]);
        w0[j] = wp.x; w1[j] = wp.y;
      }
#pragma unroll
      for (int i = 0; i < 4; i++) {
        float vin[8];
        if (useLds) {
          float4 a0 = *(const float4*)(&sAgg[wave * 4 + i][kk]);
          float4 a1 = *(const float4*)(&sAgg[wave * 4 + i][kk + 4]);
          vin[0] = a0.x; vin[1] = a0.y; vin[2] = a0.z; vin[3] = a0.w;
          vin[4] = a1.x; vin[5] = a1.y; vin[6] = a1.z; vin[7] = a1.w;
        } else {
          float4 a0 = *(const float4*)(x + (size_t)(r0 + i) * 128 + kk);
          float4 a1 = *(const float4*)(x + (size_t)(r0 + i) * 128 + kk + 4);
          vin[0] = a0.x; vin[1] = a0.y; vin[2] = a0.z; vin[3] = a0.w;
          vin[4] = a1.x; vin[5] = a1.y; vin[6] = a1.z; vin[7] = a1.w;
        }
#pragma unroll
        for (int j = 0; j < 8; j++) {
          acc0[i] = fmaf(vin[j], w0[j], acc0[i]);
          acc1[i] = fmaf(vin[j], w1[j], acc1[i]);
        }
      }
    }
  }
  float b0 = bl[co];
  float b1 = bl[co + 1];
#pragma unroll
  for (int i = 0; i < 4; i++) {
    int r = r0 + i;
    float v0 = acc0[i] + b0;
    float v1 = acc1[i] + b1;
    if (WRITE_PRE) {
      float2 p = {v0, v1};
      *(float2*)(out_pre + (size_t)r * 128 + co) = p;
    }
    float2 q = {fmaxf(v0, 0.0f), fmaxf(v1, 0.0f)};
    *(float2*)(out_relu + (size_t)r * 128 + co) = q;
  }
}

// ============== fused gather-mean + final layer (Cout=64) + log_softmax ===================
// lane owns one output col; 16KB W chunks -> 24KB LDS -> 6 blocks/CU.
__global__ __launch_bounds__(256)
void fsage64_k(const float* __restrict__ x, const int* __restrict__ row_ptr,
               const int* __restrict__ perm,
               const float* __restrict__ Wl, const float* __restrict__ bl,
               const float* __restrict__ Wr,
               float* __restrict__ out) {
  __shared__ __align__(16) float sW[64 * 64];     // 16 KB chunk
  __shared__ __align__(16) float sAgg[16][128];   // 8 KB
  int wave = threadIdx.x >> 6;
  int lane = threadIdx.x & 63;
  int r0 = blockIdx.x * 16 + wave * 4;
  int co = lane * 2;

  // ---- Phase A: gather mean into sAgg ----
#pragma unroll
  for (int i = 0; i < 4; i++) {
    int n = r0 + i;
    int beg = row_ptr[n], end = row_ptr[n + 1];
    float ax0 = 0.f, ay0 = 0.f, ax1 = 0.f, ay1 = 0.f;
    float ax2 = 0.f, ay2 = 0.f, ax3 = 0.f, ay3 = 0.f;
    int e = beg;
    for (; e + 4 <= end; e += 4) {
      int s0 = perm[e + 0], s1 = perm[e + 1], s2 = perm[e + 2], s3 = perm[e + 3];
      float2 v0 = *(const float2*)(x + (size_t)s0 * 128 + co);
      float2 v1 = *(const float2*)(x + (size_t)s1 * 128 + co);
      float2 v2 = *(const float2*)(x + (size_t)s2 * 128 + co);
      float2 v3 = *(const float2*)(x + (size_t)s3 * 128 + co);
      ax0 += v0.x; ay0 += v0.y; ax1 += v1.x; ay1 += v1.y;
      ax2 += v2.x; ay2 += v2.y; ax3 += v3.x; ay3 += v3.y;
    }
    for (; e < end; e++) {
      int s0 = perm[e];
      float2 v = *(const float2*)(x + (size_t)s0 * 128 + co);
      ax0 += v.x; ay0 += v.y;
    }
    float inv = 1.0f / fmaxf((float)(end - beg), 1.0f);
    float2 o = { (ax0 + ax1 + ax2 + ax3) * inv, (ay0 + ay1 + ay2 + ay3) * inv };
    *(float2*)(&sAgg[wave * 4 + i][co]) = o;
  }

  // ---- Phase B: GEMM over 4 chunks of 16KB ----
  float acc[4] = {0.f, 0.f, 0.f, 0.f};

  for (int half = 0; half < 4; half++) {
    const float* Wg = (half < 2) ? Wl : Wr;
    int kbase = (half & 1) * 64;
    __syncthreads();
    {
      const float4* g = (const float4*)(Wg + kbase * 64);
      float4* s = (float4*)sW;
      for (int t = threadIdx.x; t < 1024; t += 256) s[t] = g[t];
    }
    __syncthreads();
    bool useLds = (half < 2);
    for (int kb = 0; kb < 8; kb++) {
      int k0 = kb * 8;
      int kk = kbase + k0;
      float w[8];
#pragma unroll
      for (int j = 0; j < 8; j++) w[j] = sW[(k0 + j) * 64 + lane];
#pragma unroll
      for (int i = 0; i < 4; i++) {
        float vin[8];
        if (useLds) {
          float4 a0 = *(const float4*)(&sAgg[wave * 4 + i][kk]);
          float4 a1 = *(const float4*)(&sAgg[wave * 4 + i][kk + 4]);
          vin[0] = a0.x; vin[1] = a0.y; vin[2] = a0.z; vin[3] = a0.w;
          vin[4] = a1.x; vin[5] = a1.y; vin[6] = a1.z; vin[7] = a1.w;
        } else {
          float4 a0 = *(const float4*)(x + (size_t)(r0 + i) * 128 + kk);
          float4 a1 = *(const float4*)(x + (size_t)(r0 + i) * 128 + kk + 4);
          vin[0] = a0.x; vin[1] = a0.y; vin[2] = a0.z; vin[3] = a0.w;
          vin[4] = a1.x; vin[5] = a1.y; vin[6] = a1.z; vin[7] = a1.w;
        }
#pragma unroll
        for (int j = 0; j < 8; j++) acc[i] = fmaf(vin[j], w[j], acc[i]);
      }
    }
  }
  float b = bl[lane];
#pragma unroll
  for (int i = 0; i < 4; i++) {
    float v = acc[i] + b;
    float m = v;
#pragma unroll
    for (int off = 32; off > 0; off >>= 1) m = fmaxf(m, __shfl_xor(m, off));
    float e = __expf(v - m);
    float s = e;
#pragma unroll
    for (int off = 32; off > 0; off >>= 1) s += __shfl_xor(s, off);
    float ls = v - m - __logf(s);
    out[(size_t)(r0 + i) * 64 + lane] = ls;
  }
}

// ---------------- graph pooling: cluster is SORTED -> segmented mean, no atomics ----------
__global__ __launch_bounds__(128)
void pool_seg_k(const float* __restrict__ x2, const int* __restrict__ cluster,
                float* __restrict__ g) {
  int gid = blockIdx.x;          // 512
  int ch = threadIdx.x;          // 128
  int lo = 0, hi = NN;
  while (lo < hi) { int mid = (lo + hi) >> 1; if (cluster[mid] < gid) lo = mid + 1; else hi = mid; }
  int beg = lo;
  hi = NN;
  while (lo < hi) { int mid = (lo + hi) >> 1; if (cluster[mid] < gid + 1) lo = mid + 1; else hi = mid; }
  int end = lo;
  float s = 0.f;
  for (int n = beg; n < end; n++) s += x2[(size_t)n * 128 + ch];
  g[gid * 128 + ch] = s / fmaxf((float)(end - beg), 1.0f);
}

extern "C" void kernel_launch(void* const* d_in, const int* in_sizes, int n_in,
                              void* d_out, int out_size, void* d_ws, size_t ws_size,
                              hipStream_t stream) {
  const float* x   = (const float*)d_in[0];
  const int*   ei  = (const int*)d_in[1];
  const int*   cl  = (const int*)d_in[2];
  const float* Wl0 = (const float*)d_in[3];
  const float* bl0 = (const float*)d_in[4];
  const float* Wr0 = (const float*)d_in[5];
  const float* Wl1 = (const float*)d_in[6];
  const float* bl1 = (const float*)d_in[7];
  const float* Wr1 = (const float*)d_in[8];
  const float* Wl2 = (const float*)d_in[9];
  const float* bl2 = (const float*)d_in[10];
  const float* Wr2 = (const float*)d_in[11];
  float* out = (float*)d_out;

  char* ws = (char*)d_ws;
  float* x1      = (float*)(ws);                  // 25,600,000 B
  float* x2      = (float*)(ws + 25600000);       // 25,600,000 B
  int*   deg     = (int*)  (ws + 51200000);       //    200,000 B
  int*   row_ptr = (int*)  (ws + 51400192);       //    200,004 B (+pad)
  int*   cursor  = (int*)  (ws + 51600896);       //    200,000 B
  int*   perm    = (int*)  (ws + 51800896);       //  2,400,000 B

  float* out_lsm = out;            // [50000,64]
  float* out_pre = out + 3200000;  // [50000,128]
  float* out_g   = out + 9600000;  // [512,128]

  // ---- CSR build (once) ----
  hipMemsetAsync(deg, 0, 200000, stream);
  deg_count_k<<<2344, 256, 0, stream>>>(ei, deg);
  scan_k<<<1, 1024, 0, stream>>>(deg, row_ptr, cursor);
  fill_k<<<2344, 256, 0, stream>>>(ei, cursor, perm);

  // ---- layer 0 (fused gather+GEMM) ----
  fsage128_k<false><<<3125, 256, 0, stream>>>(x, row_ptr, perm, Wl0, bl0, Wr0, x1, nullptr);

  // ---- layer 1 (pre-relu straight to d_out, relu to x2) ----
  fsage128_k<true><<<3125, 256, 0, stream>>>(x1, row_ptr, perm, Wl1, bl1, Wr1, x2, out_pre);

  // ---- graph pooling of x2 ----
  pool_seg_k<<<NG, 128, 0, stream>>>(x2, cl, out_g);

  // ---- final layer + log_softmax (fused) ----
  fsage64_k<<<3125, 256, 0, stream>>>(x2, row_ptr, perm, Wl2, bl2, Wr2, out_lsm);
}

// Round 6
// 714.053 us; speedup vs baseline: 3.1270x; 3.1270x over previous
//
#include <hip/hip_runtime.h>
#include <math.h>

#define NN 50000
#define NE 600000
#define NG 512

typedef unsigned int u32;
typedef unsigned short u16;

__device__ __forceinline__ float bf2f(u16 u) {
  return __uint_as_float(((u32)u) << 16);
}
__device__ __forceinline__ u16 f2bf(float f) {
  u32 u = __float_as_uint(f);
  u32 lsb = (u >> 16) & 1u;
  u += 0x7fffu + lsb;          // RNE
  return (u16)(u >> 16);
}

// ================= CSR build (once per launch) ========
__global__ __launch_bounds__(256)
void deg_count_k(const int* __restrict__ ei, int* __restrict__ deg) {
  int e = blockIdx.x * 256 + threadIdx.x;
  if (e >= NE) return;
  atomicAdd(&deg[ei[NE + e]], 1);
}

__global__ __launch_bounds__(1024)
void scan_k(const int* __restrict__ deg, int* __restrict__ row_ptr, int* __restrict__ cursor) {
  __shared__ int sums[1024];
  const int CH = 49;                 // 1024*49 = 50176 >= 50000
  int t = threadIdx.x;
  int base = t * CH;
  int s = 0;
  for (int i = 0; i < CH; i++) { int idx = base + i; if (idx < NN) s += deg[idx]; }
  sums[t] = s;
  __syncthreads();
  for (int off = 1; off < 1024; off <<= 1) {
    int v = (t >= off) ? sums[t - off] : 0;
    __syncthreads();
    sums[t] += v;
    __syncthreads();
  }
  int prefix = (t == 0) ? 0 : sums[t - 1];
  for (int i = 0; i < CH; i++) {
    int idx = base + i;
    if (idx < NN) { row_ptr[idx] = prefix; cursor[idx] = prefix; prefix += deg[idx]; }
  }
  if (t == 1023) row_ptr[NN] = sums[1023];
}

__global__ __launch_bounds__(256)
void fill_k(const int* __restrict__ ei, int* __restrict__ cursor, int* __restrict__ perm) {
  int e = blockIdx.x * 256 + threadIdx.x;
  if (e >= NE) return;
  int pos = atomicAdd(&cursor[ei[NE + e]], 1);
  perm[pos] = ei[e];
}

// ================= cast x (f32) -> xb (bf16) =================
__global__ __launch_bounds__(256)
void cast_k(const float* __restrict__ x, u32* __restrict__ xb) {
  int tid = blockIdx.x * 256 + threadIdx.x;       // 12500*256 = 3,200,000 exactly
  float2 v = ((const float2*)x)[tid];
  xb[tid] = (u32)f2bf(v.x) | ((u32)f2bf(v.y) << 16);
}

// ===== gather-mean from bf16 features: agg[n] = mean_{e in(n)} xb[perm[e]] (f32 out) =====
// one wave per node; lane owns channels (2*lane, 2*lane+1) = one u32; 8-edge unroll.
__global__ __launch_bounds__(256)
void gather_bf_k(const u16* __restrict__ xb, const int* __restrict__ row_ptr,
                 const int* __restrict__ perm, float* __restrict__ agg) {
  int wave = threadIdx.x >> 6;
  int lane = threadIdx.x & 63;
  int n = blockIdx.x * 4 + wave;          // 12500 * 4 = 50000
  int beg = row_ptr[n], end = row_ptr[n + 1];
  int co = lane * 2;
  float ax[8], ay[8];
#pragma unroll
  for (int j = 0; j < 8; j++) { ax[j] = 0.f; ay[j] = 0.f; }
  int e = beg;
  for (; e + 8 <= end; e += 8) {
    int s[8];
#pragma unroll
    for (int j = 0; j < 8; j++) s[j] = perm[e + j];
    u32 u[8];
#pragma unroll
    for (int j = 0; j < 8; j++) u[j] = *(const u32*)(xb + (size_t)s[j] * 128 + co);
#pragma unroll
    for (int j = 0; j < 8; j++) {
      ax[j] += __uint_as_float(u[j] << 16);
      ay[j] += __uint_as_float(u[j] & 0xffff0000u);
    }
  }
  for (; e < end; e++) {
    u32 u = *(const u32*)(xb + (size_t)perm[e] * 128 + co);
    ax[0] += __uint_as_float(u << 16);
    ay[0] += __uint_as_float(u & 0xffff0000u);
  }
  float sx = (ax[0]+ax[1])+(ax[2]+ax[3])+((ax[4]+ax[5])+(ax[6]+ax[7]));
  float sy = (ay[0]+ay[1])+(ay[2]+ay[3])+((ay[4]+ay[5])+(ay[6]+ay[7]));
  float inv = 1.0f / fmaxf((float)(end - beg), 1.0f);
  float2 o = { sx * inv, sy * inv };
  *(float2*)(agg + (size_t)n * 128 + co) = o;
}

// ===== SAGE layer Cout=128: out = agg@Wl + bl + x@Wr; 32KB W chunks (4 stage passes) =====
// block 256 = 4 waves; wave owns 4 rows; lane owns cols (2*lane, 2*lane+1).
// Epilogue: optional f32 relu (x1), optional f32 pre (d_out), always bf16 relu (xb mirror).
template<bool WRITE_PRE, bool WRITE_RELU_F32>
__global__ __launch_bounds__(256)
void sage128_k(const float* __restrict__ x, const float* __restrict__ agg,
               const float* __restrict__ Wl, const float* __restrict__ bl,
               const float* __restrict__ Wr,
               float* __restrict__ out_relu, float* __restrict__ out_pre,
               u16* __restrict__ xb_out) {
  __shared__ __align__(16) float sW[64 * 128];    // 32 KB chunk
  int wave = threadIdx.x >> 6;
  int lane = threadIdx.x & 63;
  int r0 = blockIdx.x * 16 + wave * 4;            // 3125 * 16 = 50000
  int co = lane * 2;

  float acc0[4] = {0.f, 0.f, 0.f, 0.f};
  float acc1[4] = {0.f, 0.f, 0.f, 0.f};

  for (int half = 0; half < 4; half++) {
    const float* Wg = (half < 2) ? Wl : Wr;
    const float* src = (half < 2) ? agg : x;
    int kbase = (half & 1) * 64;
    __syncthreads();
    {
      const float4* g = (const float4*)(Wg + kbase * 128);
      float4* s = (float4*)sW;
      for (int t = threadIdx.x; t < 2048; t += 256) s[t] = g[t];
    }
    __syncthreads();
    for (int kb = 0; kb < 8; kb++) {
      int k0 = kb * 8;
      int kk = kbase + k0;
      float w0[8], w1[8];
#pragma unroll
      for (int j = 0; j < 8; j++) {
        float2 wp = *(const float2*)(&sW[(k0 + j) * 128 + co]);
        w0[j] = wp.x; w1[j] = wp.y;
      }
#pragma unroll
      for (int i = 0; i < 4; i++) {
        float4 a0 = *(const float4*)(src + (size_t)(r0 + i) * 128 + kk);
        float4 a1 = *(const float4*)(src + (size_t)(r0 + i) * 128 + kk + 4);
        float vin[8] = {a0.x, a0.y, a0.z, a0.w, a1.x, a1.y, a1.z, a1.w};
#pragma unroll
        for (int j = 0; j < 8; j++) {
          acc0[i] = fmaf(vin[j], w0[j], acc0[i]);
          acc1[i] = fmaf(vin[j], w1[j], acc1[i]);
        }
      }
    }
  }
  float2 bp = *(const float2*)(bl + co);
#pragma unroll
  for (int i = 0; i < 4; i++) {
    int r = r0 + i;
    float v0 = acc0[i] + bp.x;
    float v1 = acc1[i] + bp.y;
    if (WRITE_PRE) {
      float2 p = {v0, v1};
      *(float2*)(out_pre + (size_t)r * 128 + co) = p;
    }
    float r0f = fmaxf(v0, 0.0f), r1f = fmaxf(v1, 0.0f);
    if (WRITE_RELU_F32) {
      float2 q = {r0f, r1f};
      *(float2*)(out_relu + (size_t)r * 128 + co) = q;
    }
    *(u32*)(xb_out + (size_t)r * 128 + co) = (u32)f2bf(r0f) | ((u32)f2bf(r1f) << 16);
  }
}

// ===== final layer Cout=64 + log_softmax; Wl pass over f32 agg, Wr pass over bf16 x =====
__global__ __launch_bounds__(256)
void sage64_k(const u16* __restrict__ xb, const float* __restrict__ agg,
              const float* __restrict__ Wl, const float* __restrict__ bl,
              const float* __restrict__ Wr,
              float* __restrict__ out) {
  __shared__ __align__(16) float sW[128 * 64];    // 32 KB (one full W per pass)
  int wave = threadIdx.x >> 6;
  int lane = threadIdx.x & 63;
  int r0 = blockIdx.x * 16 + wave * 4;

  float acc[4] = {0.f, 0.f, 0.f, 0.f};

  for (int pass = 0; pass < 2; pass++) {
    const float* Wg = pass ? Wr : Wl;
    __syncthreads();
    {
      const float4* g = (const float4*)Wg;
      float4* s = (float4*)sW;
      for (int t = threadIdx.x; t < 2048; t += 256) s[t] = g[t];
    }
    __syncthreads();
    for (int kb = 0; kb < 16; kb++) {
      int k0 = kb * 8;
      float w[8];
#pragma unroll
      for (int j = 0; j < 8; j++) w[j] = sW[(k0 + j) * 64 + lane];
#pragma unroll
      for (int i = 0; i < 4; i++) {
        float vin[8];
        if (pass == 0) {
          float4 a0 = *(const float4*)(agg + (size_t)(r0 + i) * 128 + k0);
          float4 a1 = *(const float4*)(agg + (size_t)(r0 + i) * 128 + k0 + 4);
          vin[0] = a0.x; vin[1] = a0.y; vin[2] = a0.z; vin[3] = a0.w;
          vin[4] = a1.x; vin[5] = a1.y; vin[6] = a1.z; vin[7] = a1.w;
        } else {
          uint4 xv = *(const uint4*)(xb + (size_t)(r0 + i) * 128 + k0);
          vin[0] = __uint_as_float(xv.x << 16); vin[1] = __uint_as_float(xv.x & 0xffff0000u);
          vin[2] = __uint_as_float(xv.y << 16); vin[3] = __uint_as_float(xv.y & 0xffff0000u);
          vin[4] = __uint_as_float(xv.z << 16); vin[5] = __uint_as_float(xv.z & 0xffff0000u);
          vin[6] = __uint_as_float(xv.w << 16); vin[7] = __uint_as_float(xv.w & 0xffff0000u);
        }
#pragma unroll
        for (int j = 0; j < 8; j++) acc[i] = fmaf(vin[j], w[j], acc[i]);
      }
    }
  }
  float b = bl[lane];
#pragma unroll
  for (int i = 0; i < 4; i++) {
    float v = acc[i] + b;
    float m = v;
#pragma unroll
    for (int off = 32; off > 0; off >>= 1) m = fmaxf(m, __shfl_xor(m, off));
    float e = __expf(v - m);
    float s = e;
#pragma unroll
    for (int off = 32; off > 0; off >>= 1) s += __shfl_xor(s, off);
    float ls = v - m - __logf(s);
    out[(size_t)(r0 + i) * 64 + lane] = ls;
  }
}

// ======= graph pooling from bf16 x2 (cluster sorted -> segmented mean, no atomics) =======
__global__ __launch_bounds__(128)
void pool_seg_k(const u16* __restrict__ xb, const int* __restrict__ cluster,
                float* __restrict__ g) {
  int gid = blockIdx.x;          // 512
  int ch = threadIdx.x;          // 128
  int lo = 0, hi = NN;
  while (lo < hi) { int mid = (lo + hi) >> 1; if (cluster[mid] < gid) lo = mid + 1; else hi = mid; }
  int beg = lo;
  hi = NN;
  while (lo < hi) { int mid = (lo + hi) >> 1; if (cluster[mid] < gid + 1) lo = mid + 1; else hi = mid; }
  int end = lo;
  float s0 = 0.f, s1 = 0.f, s2 = 0.f, s3 = 0.f;
  int n = beg;
  for (; n + 4 <= end; n += 4) {
    s0 += bf2f(xb[(size_t)(n + 0) * 128 + ch]);
    s1 += bf2f(xb[(size_t)(n + 1) * 128 + ch]);
    s2 += bf2f(xb[(size_t)(n + 2) * 128 + ch]);
    s3 += bf2f(xb[(size_t)(n + 3) * 128 + ch]);
  }
  for (; n < end; n++) s0 += bf2f(xb[(size_t)n * 128 + ch]);
  float s = (s0 + s1) + (s2 + s3);
  g[gid * 128 + ch] = s / fmaxf((float)(end - beg), 1.0f);
}

extern "C" void kernel_launch(void* const* d_in, const int* in_sizes, int n_in,
                              void* d_out, int out_size, void* d_ws, size_t ws_size,
                              hipStream_t stream) {
  const float* x   = (const float*)d_in[0];
  const int*   ei  = (const int*)d_in[1];
  const int*   cl  = (const int*)d_in[2];
  const float* Wl0 = (const float*)d_in[3];
  const float* bl0 = (const float*)d_in[4];
  const float* Wr0 = (const float*)d_in[5];
  const float* Wl1 = (const float*)d_in[6];
  const float* bl1 = (const float*)d_in[7];
  const float* Wr1 = (const float*)d_in[8];
  const float* Wl2 = (const float*)d_in[9];
  const float* bl2 = (const float*)d_in[10];
  const float* Wr2 = (const float*)d_in[11];
  float* out = (float*)d_out;

  char* ws = (char*)d_ws;
  float* x1      = (float*)(ws);                  // 25,600,000 B (f32 relu of layer0)
  float* agg     = (float*)(ws + 25600000);       // 25,600,000 B
  u16*   xb      = (u16*)  (ws + 51200000);       // 12,800,000 B (bf16 mirror, reused per layer)
  int*   deg     = (int*)  (ws + 64000000);       //    200,000 B
  int*   row_ptr = (int*)  (ws + 64200192);       //    200,004 B (+pad)
  int*   cursor  = (int*)  (ws + 64400896);       //    200,000 B
  int*   perm    = (int*)  (ws + 64600896);       //  2,400,000 B
  // total ~67.0 MB

  float* out_lsm = out;            // [50000,64]
  float* out_pre = out + 3200000;  // [50000,128]
  float* out_g   = out + 9600000;  // [512,128]

  // ---- CSR build (once) ----
  hipMemsetAsync(deg, 0, 200000, stream);
  deg_count_k<<<2344, 256, 0, stream>>>(ei, deg);
  scan_k<<<1, 1024, 0, stream>>>(deg, row_ptr, cursor);
  fill_k<<<2344, 256, 0, stream>>>(ei, cursor, perm);

  // ---- layer 0 ----
  cast_k<<<12500, 256, 0, stream>>>(x, (u32*)xb);
  gather_bf_k<<<12500, 256, 0, stream>>>(xb, row_ptr, perm, agg);
  sage128_k<false, true><<<3125, 256, 0, stream>>>(x, agg, Wl0, bl0, Wr0, x1, nullptr, xb);

  // ---- layer 1 (pre-relu f32 straight to d_out; relu only as bf16 mirror) ----
  gather_bf_k<<<12500, 256, 0, stream>>>(xb, row_ptr, perm, agg);
  sage128_k<true, false><<<3125, 256, 0, stream>>>(x1, agg, Wl1, bl1, Wr1, nullptr, out_pre, xb);

  // ---- graph pooling of x2 (bf16) ----
  pool_seg_k<<<NG, 128, 0, stream>>>(xb, cl, out_g);

  // ---- final layer + log_softmax ----
  gather_bf_k<<<12500, 256, 0, stream>>>(xb, row_ptr, perm, agg);
  sage64_k<<<3125, 256, 0, stream>>>(xb, agg, Wl2, bl2, Wr2, out_lsm);
}